// Round 2
// baseline (855.908 us; speedup 1.0000x reference)
//
#include <hip/hip_runtime.h>
#include <math.h>

// ---------------- problem constants ----------------
constexpr int kN = 24000;     // nodes
constexpr int kE = 384000;    // edges
constexpr float kAlpha = 0.05f;

typedef unsigned int   u32;
typedef unsigned short u16;

// ---- bf16 helpers (internal storage format; RNE rounding) ----
__device__ __forceinline__ float bflo(u32 w) { return __uint_as_float(w << 16); }
__device__ __forceinline__ float bfhi(u32 w) { return __uint_as_float(w & 0xffff0000u); }
__device__ __forceinline__ u16 f2bf(float f) {
  u32 u = __float_as_uint(f);
  return (u16)((u + 0x7fffu + ((u >> 16) & 1u)) >> 16);
}
// decode 32-bf16 row (64B) into 32 floats
__device__ __forceinline__ void bfrow32(const u16* __restrict__ p, float* f) {
  const uint4* q = (const uint4*)p;
  #pragma unroll
  for (int i = 0; i < 4; ++i) {
    uint4 w = q[i];
    f[i*8+0] = bflo(w.x); f[i*8+1] = bfhi(w.x);
    f[i*8+2] = bflo(w.y); f[i*8+3] = bfhi(w.y);
    f[i*8+4] = bflo(w.z); f[i*8+5] = bfhi(w.z);
    f[i*8+6] = bflo(w.w); f[i*8+7] = bfhi(w.w);
  }
}

// ============================================================
// CSR build (dst-major) — graph shared across all 3 TA layers
// ============================================================
__global__ void __launch_bounds__(256) zero_ints_kernel(int* __restrict__ p, int n) {
  int i = blockIdx.x * 256 + threadIdx.x;
  if (i < n) p[i] = 0;
}

__global__ void __launch_bounds__(256) count_kernel(const int* __restrict__ dst,
                                                    int* __restrict__ counts) {
  int e = blockIdx.x * 256 + threadIdx.x;
  if (e < kE) atomicAdd(&counts[dst[e]], 1);
}

__global__ void __launch_bounds__(1024) scan_kernel(const int* __restrict__ counts,
                                                    int* __restrict__ row_start) {
  __shared__ int sdata[1024];
  __shared__ int carry_s;
  int tid = threadIdx.x;
  if (tid == 0) { carry_s = 0; row_start[0] = 0; }
  __syncthreads();
  for (int base = 0; base < kN; base += 1024) {
    int v = (base + tid < kN) ? counts[base + tid] : 0;
    sdata[tid] = v;
    __syncthreads();
    for (int off = 1; off < 1024; off <<= 1) {
      int t = (tid >= off) ? sdata[tid - off] : 0;
      __syncthreads();
      if (tid >= off) sdata[tid] += t;
      __syncthreads();
    }
    int c = carry_s;
    if (base + tid < kN) row_start[base + tid + 1] = sdata[tid] + c;
    __syncthreads();
    if (tid == 1023) carry_s = sdata[1023] + c;
    __syncthreads();
  }
}

__global__ void __launch_bounds__(256) scatter_kernel(const int* __restrict__ dst,
                                                      const int* __restrict__ row_start,
                                                      int* __restrict__ cursor,
                                                      int* __restrict__ edge_ids) {
  int e = blockIdx.x * 256 + threadIdx.x;
  if (e < kE) {
    int n = dst[e];
    int pos = row_start[n] + atomicAdd(&cursor[n], 1);
    edge_ids[pos] = e;
  }
}

// ============================================================
// Tiny precompute: ntf[3][32], eterm[l][NE][Hh], DA-layer delta.
// _ln over a singleton dim == its bias => q,k,v constant => uniform
// softmax => each DAL layer adds a data-independent scalar.
// ============================================================
__global__ void __launch_bounds__(256) precompute_kernel(
    const float* __restrict__ ntype_emb, const float* __restrict__ W_ntype,
    const float* __restrict__ emb0, const float* __restrict__ We0, const float* __restrict__ ae0,
    const float* __restrict__ emb1, const float* __restrict__ We1, const float* __restrict__ ae1,
    const float* __restrict__ emb2, const float* __restrict__ We2, const float* __restrict__ ae2,
    const float* __restrict__ ln1_b, const float* __restrict__ Wv, const float* __restrict__ bv,
    const float* __restrict__ Wo, const float* __restrict__ bo,
    const float* __restrict__ ln2_b, const float* __restrict__ W1, const float* __restrict__ b1,
    const float* __restrict__ W2, const float* __restrict__ b2,
    float* __restrict__ ntf, float* __restrict__ eterm, float* __restrict__ dadelta) {
  int tid = threadIdx.x;
  if (tid < 96) {
    int t = tid / 32, o = tid % 32;
    float s = 0.f;
    for (int k = 0; k < 32; ++k) s += ntype_emb[t * 32 + k] * W_ntype[k * 32 + o];
    ntf[tid] = s;
  } else if (tid < 96 + 85) {
    int id = tid - 96;
    const float *emb, *We, *ae; int Hh, t, h, base;
    if (id < 40)      { emb = emb0; We = We0; ae = ae0; Hh = 8; t = id / 8;        h = id % 8;        base = 0;  }
    else if (id < 80) { int i = id - 40; emb = emb1; We = We1; ae = ae1; Hh = 8; t = i / 8; h = i % 8; base = 40; }
    else              { int i = id - 80; emb = emb2; We = We2; ae = ae2; Hh = 1; t = i;     h = 0;     base = 80; }
    float s = 0.f;
    for (int d = 0; d < 64; ++d) {
      float tmp = 0.f;
      for (int k = 0; k < 64; ++k) tmp += emb[t * 64 + k] * We[k * Hh * 64 + h * 64 + d];
      s += tmp * ae[h * 64 + d];
    }
    eterm[base + t * Hh + h] = s;
  } else if (tid == 224) {
    float delta = 0.f;
    for (int l = 0; l < 2; ++l) {
      float y  = ln1_b[l];
      float vs = y * Wv[l] + bv[l];
      delta += vs * Wo[l] + bo[l];
      float y2 = ln2_b[l];
      float f  = b2[l];
      for (int j = 0; j < 64; ++j) {
        float u = y2 * W1[l * 64 + j] + b1[l * 64 + j];
        float g = 0.5f * u * (1.0f + erff(u * 0.7071067811865476f));
        f += g * W2[l * 64 + j];
      }
      delta += f;
    }
    *dadelta = delta;
  }
}

// ============================================================
// Input projection: h = lrelu(feats@fc_W + fc_b, 0.01) * ntf[node_type]
// ============================================================
__global__ void __launch_bounds__(256) inproj_kernel(
    const float* __restrict__ feats, const float* __restrict__ fc_W,
    const float* __restrict__ fc_b, const float* __restrict__ ntf,
    const int* __restrict__ node_type, float* __restrict__ h) {
  int t = blockIdx.x * 256 + threadIdx.x;
  if (t >= kN * 32) return;
  int n = t >> 5, o = t & 31;
  int ty = n / 8000;
  const float* fr = &feats[(size_t)n * 128];
  const float* w  = &fc_W[(size_t)ty * 4096 + o];
  float s = fc_b[ty * 32 + o];
  #pragma unroll
  for (int k = 0; k < 128; k += 4) {
    float4 f = *(const float4*)&fr[k];
    s += f.x * w[(k + 0) * 32] + f.y * w[(k + 1) * 32]
       + f.z * w[(k + 2) * 32] + f.w * w[(k + 3) * 32];
  }
  s = (s < 0.f) ? 0.01f * s : s;
  h[t] = s * ntf[node_type[n] * 32 + o];
}

// ============================================================
// Out-of-place GEMM: C[M][Ncol] = A[M][K] @ W[K][Ncol] (+bias)
// 128x64 tile, 256 threads, 8x4 micro-tile. OutT: float or u16(bf16).
// ============================================================
template <typename OutT, bool BIAS>
__global__ void __launch_bounds__(256) gemm_kernel(
    const float* __restrict__ A, const float* __restrict__ W,
    const float* __restrict__ bias, OutT* __restrict__ C,
    int M, int K, int Ncol) {
  __shared__ float As[16][128];
  __shared__ float Bs[16][64];
  const int tid = threadIdx.x;
  const int tr = tid >> 4;
  const int tc = tid & 15;
  const int row0 = blockIdx.y * 128;
  const int col0 = blockIdx.x * 64;
  float acc[8][4];
  #pragma unroll
  for (int i = 0; i < 8; ++i)
    #pragma unroll
    for (int j = 0; j < 4; ++j) acc[i][j] = 0.f;

  const int lr = tid >> 1;
  const int lk = (tid & 1) * 8;
  const int wk = tid >> 4;
  const int wc = (tid & 15) * 4;

  for (int kc = 0; kc < K; kc += 16) {
    int arow = row0 + lr;
    float4 v0 = make_float4(0, 0, 0, 0), v1 = v0;
    if (arow < M) {
      v0 = *(const float4*)&A[(size_t)arow * K + kc + lk];
      v1 = *(const float4*)&A[(size_t)arow * K + kc + lk + 4];
    }
    As[lk + 0][lr] = v0.x; As[lk + 1][lr] = v0.y; As[lk + 2][lr] = v0.z; As[lk + 3][lr] = v0.w;
    As[lk + 4][lr] = v1.x; As[lk + 5][lr] = v1.y; As[lk + 6][lr] = v1.z; As[lk + 7][lr] = v1.w;
    {
      float4 wv = make_float4(0, 0, 0, 0);
      int col = col0 + wc;
      if (col < Ncol) wv = *(const float4*)&W[(size_t)(kc + wk) * Ncol + col];
      *(float4*)&Bs[wk][wc] = wv;
    }
    __syncthreads();
    #pragma unroll
    for (int kk = 0; kk < 16; ++kk) {
      float4 a0 = *(const float4*)&As[kk][tr * 8];
      float4 a1 = *(const float4*)&As[kk][tr * 8 + 4];
      float4 b4 = *(const float4*)&Bs[kk][tc * 4];
      float av[8] = {a0.x, a0.y, a0.z, a0.w, a1.x, a1.y, a1.z, a1.w};
      float bv[4] = {b4.x, b4.y, b4.z, b4.w};
      #pragma unroll
      for (int i = 0; i < 8; ++i)
        #pragma unroll
        for (int j = 0; j < 4; ++j)
          acc[i][j] = fmaf(av[i], bv[j], acc[i][j]);
    }
    __syncthreads();
  }
  int col = col0 + tc * 4;
  if (col < Ncol) {                      // col multiple of 4, Ncol multiple of 4
    #pragma unroll
    for (int i = 0; i < 8; ++i) {
      int row = row0 + tr * 8 + i;
      if (row >= M) break;
      float v0 = acc[i][0], v1 = acc[i][1], v2 = acc[i][2], v3 = acc[i][3];
      if (BIAS) { v0 += bias[col]; v1 += bias[col+1]; v2 += bias[col+2]; v3 += bias[col+3]; }
      if constexpr (sizeof(OutT) == 2) {
        ushort4 p; p.x = f2bf(v0); p.y = f2bf(v1); p.z = f2bf(v2); p.w = f2bf(v3);
        *(ushort4*)&C[(size_t)row * Ncol + col] = p;
      } else {
        *(float4*)&C[(size_t)row * Ncol + col] = make_float4(v0, v1, v2, v3);
      }
    }
  }
}

// ============================================================
// In-place res GEMM: R[24000][256] = R @ W[256][256] + bias.
// One block owns 64 rows exclusively (reads its A rows, writes same
// rows in epilogue AFTER all reads) -> in-place safe. 256 thr, 8x8.
// ============================================================
__global__ void __launch_bounds__(256) gemm_inplace_kernel(
    float* __restrict__ RW, const float* __restrict__ W, const float* __restrict__ bias) {
  __shared__ float As[16][65];
  __shared__ float Bs[16][256];
  const int tid = threadIdx.x;
  const int row0 = blockIdx.x * 64;
  const int rg = tid >> 5;              // 0..7  rows rg*8..+7
  const int tx = tid & 31;              // cols tx + 32*j
  float acc[8][8];
  #pragma unroll
  for (int i = 0; i < 8; ++i)
    #pragma unroll
    for (int j = 0; j < 8; ++j) acc[i][j] = 0.f;

  const int lr = tid >> 2;              // 0..63
  const int lk = (tid & 3) * 4;         // 0,4,8,12
  const int wk = tid >> 4;              // 0..15
  const int wc = (tid & 15) * 16;       // 0..240

  for (int kc = 0; kc < 256; kc += 16) {
    float4 a4 = *(const float4*)&RW[(size_t)(row0 + lr) * 256 + kc + lk];
    As[lk + 0][lr] = a4.x; As[lk + 1][lr] = a4.y; As[lk + 2][lr] = a4.z; As[lk + 3][lr] = a4.w;
    #pragma unroll
    for (int q = 0; q < 4; ++q)
      *(float4*)&Bs[wk][wc + q * 4] = *(const float4*)&W[(size_t)(kc + wk) * 256 + wc + q * 4];
    __syncthreads();
    #pragma unroll
    for (int kk = 0; kk < 16; ++kk) {
      float a_[8];
      #pragma unroll
      for (int i = 0; i < 8; ++i) a_[i] = As[kk][rg * 8 + i];
      #pragma unroll
      for (int j = 0; j < 8; ++j) {
        float b = Bs[kk][tx + 32 * j];
        #pragma unroll
        for (int i = 0; i < 8; ++i) acc[i][j] = fmaf(a_[i], b, acc[i][j]);
      }
    }
    __syncthreads();
  }
  #pragma unroll
  for (int i = 0; i < 8; ++i) {
    int row = row0 + rg * 8 + i;
    #pragma unroll
    for (int j = 0; j < 8; ++j) {
      int col = tx + 32 * j;
      RW[(size_t)row * 256 + col] = acc[i][j] + bias[col];
    }
  }
}

// ============================================================
// el/er from bf16 feat
// ============================================================
template <int HH>
__global__ void __launch_bounds__(256) elr_kernel(
    const u16* __restrict__ featb, const float* __restrict__ al,
    const float* __restrict__ ar, float* __restrict__ el, float* __restrict__ er) {
  int t = blockIdx.x * 256 + threadIdx.x;
  if (t >= kN * HH) return;
  int h = t % HH;
  float f[32];
  bfrow32(&featb[(size_t)t * 32], f);
  const float* a = &al[h * 32];
  const float* r = &ar[h * 32];
  float sl = 0.f, sr = 0.f;
  #pragma unroll
  for (int d = 0; d < 32; ++d) { sl += f[d] * a[d]; sr += f[d] * r[d]; }
  el[t] = sl; er[t] = sr;
}

// ============================================================
// Edge-softmax aggregation, atomic-free: one thread per (node, head).
// acc init: bias (L0) / in-place accumulate into rst (L1 res, L2 res).
// ============================================================
template <int HH, bool WRITE_A0, bool READ_A0, bool BIAS_INIT, bool ACC_IN, bool ACT>
__global__ void __launch_bounds__(256) agg_kernel(
    const int* __restrict__ row_start, const int* __restrict__ edge_ids,
    const int* __restrict__ src, const int* __restrict__ ef,
    const float* __restrict__ el, const float* __restrict__ er,
    const float* __restrict__ eterm,        // [NE][HH]
    const u16* __restrict__ featb,          // [N][HH][32] bf16
    const float* __restrict__ bias,         // [HH][32] (BIAS_INIT)
    _Float16* __restrict__ a0,              // [E][8]
    float* __restrict__ rst) {              // [N][HH][32] fp32 (in-place acc)
  int t = blockIdx.x * 256 + threadIdx.x;
  if (t >= kN * HH) return;
  int n = (HH == 1) ? t : (t / HH);
  int h = (HH == 1) ? 0 : (t % HH);
  int s0 = row_start[n], s1 = row_start[n + 1];
  float ern = er[t];
  float acc[32];
  if (BIAS_INIT) {
    #pragma unroll
    for (int d = 0; d < 32; ++d) acc[d] = bias[h * 32 + d];
  } else if (ACC_IN) {
    #pragma unroll
    for (int q = 0; q < 8; ++q) {
      float4 v = *(const float4*)&rst[(size_t)t * 32 + q * 4];
      acc[q*4] = v.x; acc[q*4+1] = v.y; acc[q*4+2] = v.z; acc[q*4+3] = v.w;
    }
  } else {
    #pragma unroll
    for (int d = 0; d < 32; ++d) acc[d] = 0.f;
  }
  if (s0 < s1) {
    float m = -1e30f, ssum = 0.f;
    for (int i = s0; i < s1; ++i) {
      int e = edge_ids[i];
      float lg = el[src[e] * HH + h] + ern + eterm[ef[e] * HH + h];
      lg = (lg < 0.f) ? 0.2f * lg : lg;
      if (lg > m) { ssum = ssum * expf(m - lg) + 1.f; m = lg; }
      else        { ssum += expf(lg - m); }
    }
    float inv = 1.f / ssum;
    for (int i = s0; i < s1; ++i) {
      int e = edge_ids[i];
      int se = src[e];
      float lg = el[se * HH + h] + ern + eterm[ef[e] * HH + h];
      lg = (lg < 0.f) ? 0.2f * lg : lg;
      float a = expf(lg - m) * inv;
      if (WRITE_A0) a0[(size_t)e * 8 + h] = (_Float16)a;
      if (READ_A0)  a = a * (1.f - kAlpha) + (float)a0[(size_t)e * 8 + h] * kAlpha;
      float f[32];
      bfrow32(&featb[((size_t)se * HH + h) * 32], f);
      #pragma unroll
      for (int d = 0; d < 32; ++d) acc[d] = fmaf(a, f[d], acc[d]);
    }
  }
  #pragma unroll
  for (int q = 0; q < 8; ++q) {
    float4 v;
    v.x = acc[q*4]; v.y = acc[q*4+1]; v.z = acc[q*4+2]; v.w = acc[q*4+3];
    if (ACT) {
      v.x = (v.x > 0.f) ? v.x : expm1f(v.x);
      v.y = (v.y > 0.f) ? v.y : expm1f(v.y);
      v.z = (v.z > 0.f) ? v.z : expm1f(v.z);
      v.w = (v.w > 0.f) ? v.w : expm1f(v.w);
    }
    *(float4*)&rst[(size_t)t * 32 + q * 4] = v;
  }
}

// ============================================================
// Final head: l2n(h_feat) ++ l2n(h_feat*ntf + delta) @ final_W,
// relu, @ logits_W, row l2-normalize.
// ============================================================
__global__ void __launch_bounds__(256) final_kernel(
    const float* __restrict__ hfeat, const float* __restrict__ ntf,
    const int* __restrict__ node_type, const float* __restrict__ dadelta,
    const float* __restrict__ finalW, const float* __restrict__ logitsW,
    float* __restrict__ out) {
  int n = blockIdx.x * 256 + threadIdx.x;
  if (n >= kN) return;
  float delta = dadelta[0];
  const float* hf = &hfeat[(size_t)n * 32];
  const float* nt = &ntf[node_type[n] * 32];
  float a[32], b[32];
  float na = 0.f, nb = 0.f;
  #pragma unroll
  for (int d = 0; d < 32; ++d) {
    float x = hf[d];
    a[d] = x; na += x * x;
    float y = x * nt[d] + delta;
    b[d] = y; nb += y * y;
  }
  float inva = 1.f / fmaxf(sqrtf(na), 1e-12f);
  float invb = 1.f / fmaxf(sqrtf(nb), 1e-12f);
  #pragma unroll
  for (int d = 0; d < 32; ++d) { a[d] *= inva; b[d] *= invb; }
  float lg[16];
  #pragma unroll
  for (int c = 0; c < 16; ++c) lg[c] = 0.f;
  for (int o = 0; o < 32; ++o) {
    float s = 0.f;
    #pragma unroll
    for (int d = 0; d < 32; ++d)
      s += a[d] * finalW[d * 32 + o] + b[d] * finalW[(32 + d) * 32 + o];
    s = fmaxf(s, 0.f);
    #pragma unroll
    for (int c = 0; c < 16; ++c) lg[c] += s * logitsW[o * 16 + c];
  }
  float nl = 0.f;
  #pragma unroll
  for (int c = 0; c < 16; ++c) nl += lg[c] * lg[c];
  float invl = 1.f / fmaxf(sqrtf(nl), 1e-12f);
  #pragma unroll
  for (int c = 0; c < 16; ++c) out[(size_t)n * 16 + c] = lg[c] * invl;
}

// ============================================================
extern "C" void kernel_launch(void* const* d_in, const int* in_sizes, int n_in,
                              void* d_out, int out_size, void* d_ws, size_t ws_size,
                              hipStream_t stream) {
  const float* feats     = (const float*)d_in[0];
  const int*   e_feat    = (const int*)d_in[1];
  const int*   node_type = (const int*)d_in[2];
  const int*   src       = (const int*)d_in[3];
  const int*   dst       = (const int*)d_in[4];
  const float* fc_W      = (const float*)d_in[5];
  const float* fc_b      = (const float*)d_in[6];
  const float* ntype_emb = (const float*)d_in[7];
  const float* W_ntype   = (const float*)d_in[8];
  const float* ta_edge_emb[3] = {(const float*)d_in[9],  (const float*)d_in[16], (const float*)d_in[24]};
  const float* ta_W[3]        = {(const float*)d_in[10], (const float*)d_in[17], (const float*)d_in[25]};
  const float* ta_We[3]       = {(const float*)d_in[11], (const float*)d_in[18], (const float*)d_in[26]};
  const float* ta_al[3]       = {(const float*)d_in[12], (const float*)d_in[19], (const float*)d_in[27]};
  const float* ta_ar[3]       = {(const float*)d_in[13], (const float*)d_in[20], (const float*)d_in[28]};
  const float* ta_ae[3]       = {(const float*)d_in[14], (const float*)d_in[21], (const float*)d_in[29]};
  const float* ta_bias[3]     = {(const float*)d_in[15], (const float*)d_in[22], (const float*)d_in[30]};
  const float* ta1_res_W = (const float*)d_in[23];
  const float* ta2_res_W = (const float*)d_in[31];
  const float* da_ln1_b  = (const float*)d_in[33];
  const float* da_Wv     = (const float*)d_in[38];
  const float* da_bv     = (const float*)d_in[39];
  const float* da_Wo     = (const float*)d_in[40];
  const float* da_bo     = (const float*)d_in[41];
  const float* da_ln2_b  = (const float*)d_in[43];
  const float* da_W1     = (const float*)d_in[44];
  const float* da_b1     = (const float*)d_in[45];
  const float* da_W2     = (const float*)d_in[46];
  const float* da_b2     = (const float*)d_in[47];
  const float* final_W   = (const float*)d_in[48];
  const float* logits_W  = (const float*)d_in[49];
  float* out = (float*)d_out;

  // ---- workspace layout: 52.5 MB total (ints first) ----
  char* base = (char*)d_ws;
  int* iws       = (int*)base;
  int* counts    = iws;                       // kN
  int* cursor    = iws + kN;                  // kN
  int* row_start = iws + 2 * kN;              // kN+1
  int* edge_ids  = iws + 2 * kN + kN + 1;     // kE
  // pad int region to 456004 ints (16B alignment for float region)
  float* fws = (float*)(base + (size_t)456004 * 4);
  float* ntf = fws;            // 128
  float* etm = fws + 128;      // 128
  float* dad = fws + 256;      // 16  (272 total -> 1088B, 16B aligned)
  float* el  = fws + 272;                       // kN*8
  float* er  = el + (size_t)kN * 8;             // kN*8
  float* H   = er + (size_t)kN * 8;             // kN*32  (input h)
  float* S2  = H  + (size_t)kN * 32;            // kN*32  (layer-2 res/out)
  _Float16* a0h = (_Float16*)(S2 + (size_t)kN * 32);          // E*8 halves
  u16* featb    = (u16*)((char*)a0h + (size_t)kE * 8 * 2);    // kN*256 bf16
  float* R      = (float*)((char*)featb + (size_t)kN * 256 * 2);  // kN*256 fp32

  // --- CSR build ---
  zero_ints_kernel<<<(2 * kN + 255) / 256, 256, 0, stream>>>(counts, 2 * kN);
  count_kernel<<<kE / 256, 256, 0, stream>>>(dst, counts);
  scan_kernel<<<1, 1024, 0, stream>>>(counts, row_start);
  scatter_kernel<<<kE / 256, 256, 0, stream>>>(dst, row_start, cursor, edge_ids);

  // --- tiny precompute ---
  precompute_kernel<<<1, 256, 0, stream>>>(
      ntype_emb, W_ntype,
      ta_edge_emb[0], ta_We[0], ta_ae[0],
      ta_edge_emb[1], ta_We[1], ta_ae[1],
      ta_edge_emb[2], ta_We[2], ta_ae[2],
      da_ln1_b, da_Wv, da_bv, da_Wo, da_bo,
      da_ln2_b, da_W1, da_b1, da_W2, da_b2,
      ntf, etm, dad);

  // --- input projection -> H [N][32] ---
  inproj_kernel<<<(kN * 32) / 256, 256, 0, stream>>>(feats, fc_W, fc_b, ntf, node_type, H);

  dim3 gf(4, (kN + 127) / 128);   // Ncol=256
  dim3 gs(1, (kN + 127) / 128);   // Ncol=32

  // --- TA layer 0 (Hh=8): feat=H@W0 -> bf16; agg init=bias, elu, writes a0 ---
  gemm_kernel<u16, false><<<gf, 256, 0, stream>>>(H, ta_W[0], nullptr, featb, kN, 32, 256);
  elr_kernel<8><<<(kN * 8) / 256, 256, 0, stream>>>(featb, ta_al[0], ta_ar[0], el, er);
  agg_kernel<8, true, false, true, false, true><<<(kN * 8) / 256, 256, 0, stream>>>(
      row_start, edge_ids, src, e_feat, el, er, etm, featb, ta_bias[0], a0h, R);

  // --- TA layer 1 (Hh=8): feat=R@W1; R <- R@resW1+bias (in-place);
  //     agg accumulates into R, blends a0, elu ---
  gemm_kernel<u16, false><<<gf, 256, 0, stream>>>(R, ta_W[1], nullptr, featb, kN, 256, 256);
  gemm_inplace_kernel<<<kN / 64, 256, 0, stream>>>(R, ta1_res_W, ta_bias[1]);
  elr_kernel<8><<<(kN * 8) / 256, 256, 0, stream>>>(featb, ta_al[1], ta_ar[1], el, er);
  agg_kernel<8, false, true, false, true, true><<<(kN * 8) / 256, 256, 0, stream>>>(
      row_start, edge_ids, src, e_feat, el, er, etm + 40, featb, nullptr, a0h, R);

  // --- TA layer 2 (Hh=1): feat=R@W2 (bf16, small); S2=R@resW2+bias;
  //     agg accumulates into S2, no act ---
  gemm_kernel<u16, false><<<gs, 256, 0, stream>>>(R, ta_W[2], nullptr, featb, kN, 256, 32);
  gemm_kernel<float, true><<<gs, 256, 0, stream>>>(R, ta2_res_W, ta_bias[2], S2, kN, 256, 32);
  elr_kernel<1><<<(kN + 255) / 256, 256, 0, stream>>>(featb, ta_al[2], ta_ar[2], el, er);
  agg_kernel<1, false, false, false, true, false><<<(kN + 255) / 256, 256, 0, stream>>>(
      row_start, edge_ids, src, e_feat, el, er, etm + 80, featb, nullptr, a0h, S2);

  // --- DA collapse + final head ---
  final_kernel<<<(kN + 255) / 256, 256, 0, stream>>>(S2, ntf, node_type, dad, final_W, logits_W, out);
}

// Round 3
// 603.096 us; speedup vs baseline: 1.4192x; 1.4192x over previous
//
#include <hip/hip_runtime.h>
#include <math.h>

// ---------------- problem constants ----------------
constexpr int kN = 24000;     // nodes
constexpr int kE = 384000;    // edges
constexpr float kAlpha = 0.05f;

typedef unsigned int   u32;
typedef unsigned short u16;
typedef __attribute__((ext_vector_type(8))) short short8;
typedef __attribute__((ext_vector_type(4))) float float4v;

// ---- bf16 helpers (internal storage; RNE) ----
__device__ __forceinline__ float bf2f(u16 x) { return __uint_as_float(((u32)x) << 16); }
__device__ __forceinline__ u16 f2bf(float f) {
  u32 u = __float_as_uint(f);
  return (u16)((u + 0x7fffu + ((u >> 16) & 1u)) >> 16);
}
__device__ __forceinline__ void bfrow32(const u16* __restrict__ p, float* f) {
  const uint4* q = (const uint4*)p;
  #pragma unroll
  for (int i = 0; i < 4; ++i) {
    uint4 w = q[i];
    f[i*8+0] = bf2f((u16)(w.x & 0xffff)); f[i*8+1] = bf2f((u16)(w.x >> 16));
    f[i*8+2] = bf2f((u16)(w.y & 0xffff)); f[i*8+3] = bf2f((u16)(w.y >> 16));
    f[i*8+4] = bf2f((u16)(w.z & 0xffff)); f[i*8+5] = bf2f((u16)(w.z >> 16));
    f[i*8+6] = bf2f((u16)(w.w & 0xffff)); f[i*8+7] = bf2f((u16)(w.w >> 16));
  }
}

// ============================================================
// CSR build
// ============================================================
__global__ void __launch_bounds__(256) zero_ints_kernel(int* __restrict__ p, int n) {
  int i = blockIdx.x * 256 + threadIdx.x;
  if (i < n) p[i] = 0;
}

__global__ void __launch_bounds__(256) count_kernel(const int* __restrict__ dst,
                                                    int* __restrict__ counts) {
  int e = blockIdx.x * 256 + threadIdx.x;
  if (e < kE) atomicAdd(&counts[dst[e]], 1);
}

// single-block scan, wave-shuffle based (2 barriers per 1024 chunk)
__global__ void __launch_bounds__(1024) scan_kernel(const int* __restrict__ counts,
                                                    int* __restrict__ row_start) {
  __shared__ int wsum[16];
  __shared__ int carry_s;
  int tid = threadIdx.x, lane = tid & 63, wid = tid >> 6;
  if (tid == 0) { carry_s = 0; row_start[0] = 0; }
  __syncthreads();
  for (int base = 0; base < kN; base += 1024) {
    int x = (base + tid < kN) ? counts[base + tid] : 0;
    #pragma unroll
    for (int off = 1; off < 64; off <<= 1) {
      int y = __shfl_up(x, off);
      if (lane >= off) x += y;
    }
    if (lane == 63) wsum[wid] = x;
    __syncthreads();
    if (tid < 16) {
      int wv = wsum[tid];
      #pragma unroll
      for (int off = 1; off < 16; off <<= 1) {
        int y = __shfl_up(wv, off);
        if (tid >= off) wv += y;
      }
      wsum[tid] = wv;
    }
    __syncthreads();
    int incl = x + carry_s + (wid > 0 ? wsum[wid - 1] : 0);
    if (base + tid < kN) row_start[base + tid + 1] = incl;
    __syncthreads();
    if (tid == 1023) carry_s = incl;
    __syncthreads();
  }
}

__global__ void __launch_bounds__(256) scatter_kernel(const int* __restrict__ dst,
                                                      const int* __restrict__ row_start,
                                                      int* __restrict__ cursor,
                                                      int* __restrict__ edge_ids) {
  int e = blockIdx.x * 256 + threadIdx.x;
  if (e < kE) {
    int n = dst[e];
    int pos = row_start[n] + atomicAdd(&cursor[n], 1);
    edge_ids[pos] = e;
  }
}

// ============================================================
// Parallel precompute: eterm via 2-stage factorization
//   eterm[t,h] = sum_k emb[t,k] * wae[h,k],  wae[h,k] = sum_d We[k,h*64+d]*ae[h,d]
// plus ntf[3][32] and the DA-layer scalar delta (LN over singleton dim
// == its bias => q,k,v constant => uniform softmax => x += delta).
// ============================================================
__global__ void __launch_bounds__(1024) precompute_kernel(
    const float* __restrict__ ntype_emb, const float* __restrict__ W_ntype,
    const float* __restrict__ emb0, const float* __restrict__ We0, const float* __restrict__ ae0,
    const float* __restrict__ emb1, const float* __restrict__ We1, const float* __restrict__ ae1,
    const float* __restrict__ emb2, const float* __restrict__ We2, const float* __restrict__ ae2,
    const float* __restrict__ ln1_b, const float* __restrict__ Wv, const float* __restrict__ bv,
    const float* __restrict__ Wo, const float* __restrict__ bo,
    const float* __restrict__ ln2_b, const float* __restrict__ W1, const float* __restrict__ b1,
    const float* __restrict__ W2, const float* __restrict__ b2,
    float* __restrict__ ntf, float* __restrict__ eterm, float* __restrict__ dadelta) {
  __shared__ float wae[17][64];
  __shared__ float red[128];
  int tid = threadIdx.x;
  // phase 1: wae[hg][k]
  for (int idx = tid; idx < 17 * 64; idx += 1024) {
    int hg = idx >> 6, k = idx & 63;
    const float* We; const float* ae; int Hh, h;
    if (hg < 8)       { We = We0; ae = ae0; Hh = 8; h = hg; }
    else if (hg < 16) { We = We1; ae = ae1; Hh = 8; h = hg - 8; }
    else              { We = We2; ae = ae2; Hh = 1; h = 0; }
    float s = 0.f;
    for (int d = 0; d < 64; ++d) s += We[(size_t)k * Hh * 64 + h * 64 + d] * ae[h * 64 + d];
    wae[hg][k] = s;
  }
  __syncthreads();
  // phase 2
  if (tid < 85) {                       // eterm
    int id = tid;
    const float* emb; int Hh, t, h, hg, base;
    if (id < 40)      { emb = emb0; Hh = 8; t = id / 8;  h = id % 8; hg = h;      base = 0;  }
    else if (id < 80) { int i = id - 40; emb = emb1; Hh = 8; t = i / 8; h = i % 8; hg = 8 + h; base = 40; }
    else              { int i = id - 80; emb = emb2; Hh = 1; t = i;    h = 0;     hg = 16;    base = 80; }
    float s = 0.f;
    for (int k = 0; k < 64; ++k) s += emb[t * 64 + k] * wae[hg][k];
    eterm[base + t * Hh + h] = s;
  } else if (tid >= 128 && tid < 224) { // ntf
    int idx = tid - 128;
    int t = idx / 32, o = idx % 32;
    float s = 0.f;
    for (int k = 0; k < 32; ++k) s += ntype_emb[t * 32 + k] * W_ntype[k * 32 + o];
    ntf[idx] = s;
  } else if (tid >= 256 && tid < 384) { // gelu terms of delta
    int i2 = tid - 256;
    int l = i2 >> 6, j = i2 & 63;
    float u = ln2_b[l] * W1[l * 64 + j] + b1[l * 64 + j];
    float g = 0.5f * u * (1.0f + erff(u * 0.7071067811865476f));
    red[i2] = g * W2[l * 64 + j];
  }
  __syncthreads();
  if (tid == 0) {
    float delta = 0.f;
    for (int l = 0; l < 2; ++l) {
      float vs = ln1_b[l] * Wv[l] + bv[l];
      delta += vs * Wo[l] + bo[l] + b2[l];
    }
    for (int i = 0; i < 128; ++i) delta += red[i];
    *dadelta = delta;
  }
}

// ============================================================
// Weight pack: WT[l] (bf16, [Ntot][K] "B-transposed") =
//   [ feat cols | el cols | er cols | res cols | zero pad ]
// el col h:  w[k] = sum_d W[k][h*32+d] * al[h][d]   (el is linear in A!)
// ============================================================
__global__ void __launch_bounds__(256) pack_kernel(
    const float* __restrict__ W0, const float* __restrict__ al0, const float* __restrict__ ar0,
    const float* __restrict__ W1, const float* __restrict__ al1, const float* __restrict__ ar1,
    const float* __restrict__ rW1,
    const float* __restrict__ W2, const float* __restrict__ al2, const float* __restrict__ ar2,
    const float* __restrict__ rW2,
    u16* __restrict__ WT0, u16* __restrict__ WT1, u16* __restrict__ WT2) {
  const int SZ0 = 320 * 32, SZ1 = 576 * 256;
  int tid = blockIdx.x * 256 + threadIdx.x;
  float v = 0.f;
  if (tid < SZ0) {
    int n = tid / 32, k = tid % 32;
    if (n < 256) v = W0[k * 256 + n];
    else if (n < 264) { int h = n - 256; for (int d = 0; d < 32; ++d) v += W0[k * 256 + h * 32 + d] * al0[h * 32 + d]; }
    else if (n < 272) { int h = n - 264; for (int d = 0; d < 32; ++d) v += W0[k * 256 + h * 32 + d] * ar0[h * 32 + d]; }
    WT0[n * 32 + k] = f2bf(v);
  } else if (tid < SZ0 + SZ1) {
    int i = tid - SZ0;
    int n = i / 256, k = i % 256;
    if (n < 256) v = W1[k * 256 + n];
    else if (n < 264) { int h = n - 256; for (int d = 0; d < 32; ++d) v += W1[k * 256 + h * 32 + d] * al1[h * 32 + d]; }
    else if (n < 272) { int h = n - 264; for (int d = 0; d < 32; ++d) v += W1[k * 256 + h * 32 + d] * ar1[h * 32 + d]; }
    else if (n < 528) v = rW1[k * 256 + (n - 272)];
    WT1[n * 256 + k] = f2bf(v);
  } else {
    int i = tid - SZ0 - SZ1;
    int n = i / 256, k = i % 256;
    if (n < 32) v = W2[k * 32 + n];
    else if (n == 32) { for (int d = 0; d < 32; ++d) v += W2[k * 32 + d] * al2[d]; }
    else if (n == 33) { for (int d = 0; d < 32; ++d) v += W2[k * 32 + d] * ar2[d]; }
    else if (n < 66) v = rW2[k * 32 + (n - 34)];
    WT2[n * 256 + k] = f2bf(v);
  }
}

// ============================================================
// Input projection -> Hb bf16
// ============================================================
__global__ void __launch_bounds__(256) inproj_kernel(
    const float* __restrict__ feats, const float* __restrict__ fc_W,
    const float* __restrict__ fc_b, const float* __restrict__ ntf,
    const int* __restrict__ node_type, u16* __restrict__ hb) {
  int t = blockIdx.x * 256 + threadIdx.x;
  if (t >= kN * 32) return;
  int n = t >> 5, o = t & 31;
  int ty = n / 8000;
  const float* fr = &feats[(size_t)n * 128];
  const float* w  = &fc_W[(size_t)ty * 4096 + o];
  float s = fc_b[ty * 32 + o];
  #pragma unroll
  for (int k = 0; k < 128; k += 4) {
    float4 f = *(const float4*)&fr[k];
    s += f.x * w[(k + 0) * 32] + f.y * w[(k + 1) * 32]
       + f.z * w[(k + 2) * 32] + f.w * w[(k + 3) * 32];
  }
  s = (s < 0.f) ? 0.01f * s : s;
  hb[t] = f2bf(s * ntf[node_type[n] * 32 + o]);
}

// ============================================================
// bf16 MFMA GEMM, fused multi-output:
//   cols [0,N1)            -> featb (bf16)
//   cols [N1,N1+HH)        -> el (f32)
//   cols [N1+HH,N1+2HH)    -> er (f32)
//   cols [..,..+N2)        -> res + bias -> resb(bf16) or resf(f32)
// 64x64 block tile, 4 waves (2x2), each 32x32 via 2x2 16x16x32 frags.
// B-slice staged once in LDS (XOR-swizzled vs 16-way bank conflict).
// ============================================================
__global__ void __launch_bounds__(256) mfma_gemm_kernel(
    const u16* __restrict__ A, const u16* __restrict__ WT,
    const float* __restrict__ bias,
    u16* __restrict__ featb, float* __restrict__ el, float* __restrict__ er,
    u16* __restrict__ resb, float* __restrict__ resf,
    int K, int N1, int HH, int N2) {
  __shared__ __align__(16) u16 BsT[64 * 256];
  __shared__ __align__(16) u16 As[64 * 32];
  const int tid = threadIdx.x;
  const int l = tid & 63;
  const int w = tid >> 6;
  const int wm = w >> 1, wn = w & 1;
  const int m0 = blockIdx.y * 64;
  const int n0 = blockIdx.x * 64;
  const int kslot = l >> 4;
  const int l15 = l & 15;

  { // stage B-slice (rows n0..n0+63 of WT), swizzled
    const int cpr = K >> 3;
    const int total = 64 * cpr;
    for (int c = tid; c < total; c += 256) {
      int row = c / cpr, ch = c - row * cpr;
      uint4 v = *(const uint4*)(WT + (size_t)(n0 + row) * K + ch * 8);
      int off = ((row * K + ch * 8) * 2) ^ ((row & 7) << 4);
      *(uint4*)((char*)BsT + off) = v;
    }
  }

  float4v acc[2][2];
  #pragma unroll
  for (int f = 0; f < 2; ++f)
    #pragma unroll
    for (int g = 0; g < 2; ++g) { acc[f][g][0]=0.f; acc[f][g][1]=0.f; acc[f][g][2]=0.f; acc[f][g][3]=0.f; }

  for (int kc = 0; kc < K; kc += 32) {
    __syncthreads();
    { // stage A tile (64 rows x 32 k), swizzled
      int row = tid >> 2, ks = tid & 3;
      uint4 v = *(const uint4*)(A + (size_t)(m0 + row) * K + kc + ks * 8);
      int off = (row * 64 + ks * 16) ^ ((row & 7) << 4);
      *(uint4*)((char*)As + off) = v;
    }
    __syncthreads();
    short8 af[2], bf[2];
    #pragma unroll
    for (int f = 0; f < 2; ++f) {
      int row = wm * 32 + f * 16 + l15;
      int off = (row * 64 + kslot * 16) ^ ((row & 7) << 4);
      af[f] = *(const short8*)((const char*)As + off);
    }
    #pragma unroll
    for (int g = 0; g < 2; ++g) {
      int n = wn * 32 + g * 16 + l15;
      int off = ((n * K + kc + kslot * 8) * 2) ^ ((n & 7) << 4);
      bf[g] = *(const short8*)((const char*)BsT + off);
    }
    #pragma unroll
    for (int f = 0; f < 2; ++f)
      #pragma unroll
      for (int g = 0; g < 2; ++g)
        acc[f][g] = __builtin_amdgcn_mfma_f32_16x16x32_bf16(af[f], bf[g], acc[f][g], 0, 0, 0);
  }

  const int rbase = kslot * 4;
  #pragma unroll
  for (int f = 0; f < 2; ++f) {
    #pragma unroll
    for (int g = 0; g < 2; ++g) {
      int gc = n0 + wn * 32 + g * 16 + l15;
      #pragma unroll
      for (int reg = 0; reg < 4; ++reg) {
        int gr = m0 + wm * 32 + f * 16 + rbase + reg;
        float v = acc[f][g][reg];
        if (gc < N1) {
          featb[(size_t)gr * N1 + gc] = f2bf(v);
        } else if (gc < N1 + HH) {
          el[(size_t)gr * HH + (gc - N1)] = v;
        } else if (gc < N1 + 2 * HH) {
          er[(size_t)gr * HH + (gc - N1 - HH)] = v;
        } else if (gc < N1 + 2 * HH + N2) {
          int c2 = gc - N1 - 2 * HH;
          float vv = v + bias[c2];
          if (resb) resb[(size_t)gr * N2 + c2] = f2bf(vv);
          else      resf[(size_t)gr * N2 + c2] = vv;
        }
      }
    }
  }
}

// ============================================================
// Wave-per-node edge-softmax aggregation (HH=8).
// lane = h*8+s: head h, dim-quarter s. Pass2 featb read is one
// coalesced 512B transaction per edge. Softmax reduce: shfl_xor 1,2,4.
// ============================================================
template <bool WRITE_A0, bool READ_A0, bool BIAS_INIT, bool ACT>
__global__ void __launch_bounds__(256) agg8w_kernel(
    const int* __restrict__ row_start, const int* __restrict__ edge_ids,
    const int* __restrict__ src, const int* __restrict__ ef,
    const float* __restrict__ el, const float* __restrict__ er,
    const float* __restrict__ eterm,        // [NE][8]
    const u16* __restrict__ featb,          // [N][256] bf16
    const float* __restrict__ bias,         // [256] (BIAS_INIT)
    _Float16* __restrict__ a0h,             // [E][8]
    const u16* __restrict__ accb,           // [N][256] bf16 (else)
    u16* __restrict__ outb) {               // [N][256] bf16
  int gw = (blockIdx.x * 256 + threadIdx.x) >> 6;
  if (gw >= kN) return;
  int l = threadIdx.x & 63;
  int h = l >> 3, s = l & 7;
  int s0 = row_start[gw], s1 = row_start[gw + 1];
  float ern = er[gw * 8 + h];
  // pass 1: per-lane online (max,sum) over every 8th edge
  float m = -1e30f, ssum = 0.f;
  for (int i = s0 + s; i < s1; i += 8) {
    int e = edge_ids[i];
    float lg = el[src[e] * 8 + h] + ern + eterm[ef[e] * 8 + h];
    lg = (lg < 0.f) ? 0.2f * lg : lg;
    if (lg > m) { ssum = ssum * expf(m - lg) + 1.f; m = lg; }
    else        { ssum += expf(lg - m); }
  }
  #pragma unroll
  for (int mk = 1; mk <= 4; mk <<= 1) {
    float om = __shfl_xor(m, mk);
    float os = __shfl_xor(ssum, mk);
    float nm = fmaxf(m, om);
    ssum = ssum * expf(m - nm) + os * expf(om - nm);
    m = nm;
  }
  float inv = 1.f / ssum;
  // acc init
  float4 acc;
  if (BIAS_INIT) {
    acc = *(const float4*)(bias + h * 32 + s * 4);
  } else {
    ushort4 rv = *(const ushort4*)(accb + (size_t)gw * 256 + l * 4);
    acc = make_float4(bf2f(rv.x), bf2f(rv.y), bf2f(rv.z), bf2f(rv.w));
  }
  // pass 2: all lanes walk all edges together
  for (int i = s0; i < s1; ++i) {
    int e = edge_ids[i];
    int se = src[e];
    float lg = el[se * 8 + h] + ern + eterm[ef[e] * 8 + h];
    lg = (lg < 0.f) ? 0.2f * lg : lg;
    float a = expf(lg - m) * inv;
    if (WRITE_A0) { if (s == 0) a0h[(size_t)e * 8 + h] = (_Float16)a; }
    if (READ_A0)  a = a * (1.f - kAlpha) + (float)a0h[(size_t)e * 8 + h] * kAlpha;
    ushort4 fv = *(const ushort4*)(featb + (size_t)se * 256 + l * 4);
    acc.x = fmaf(a, bf2f(fv.x), acc.x);
    acc.y = fmaf(a, bf2f(fv.y), acc.y);
    acc.z = fmaf(a, bf2f(fv.z), acc.z);
    acc.w = fmaf(a, bf2f(fv.w), acc.w);
  }
  if (ACT) {
    acc.x = (acc.x > 0.f) ? acc.x : expm1f(acc.x);
    acc.y = (acc.y > 0.f) ? acc.y : expm1f(acc.y);
    acc.z = (acc.z > 0.f) ? acc.z : expm1f(acc.z);
    acc.w = (acc.w > 0.f) ? acc.w : expm1f(acc.w);
  }
  ushort4 p;
  p.x = f2bf(acc.x); p.y = f2bf(acc.y); p.z = f2bf(acc.z); p.w = f2bf(acc.w);
  *(ushort4*)(outb + (size_t)gw * 256 + l * 4) = p;
}

// ============================================================
// HH=1 per-thread aggregation (L2): acc in/out S2 fp32, no act
// ============================================================
__global__ void __launch_bounds__(256) agg1t_kernel(
    const int* __restrict__ row_start, const int* __restrict__ edge_ids,
    const int* __restrict__ src, const int* __restrict__ ef,
    const float* __restrict__ el, const float* __restrict__ er,
    const float* __restrict__ eterm,        // [NE]
    const u16* __restrict__ featb,          // [N][32] bf16
    float* __restrict__ rst) {              // [N][32] fp32 in/out
  int t = blockIdx.x * 256 + threadIdx.x;
  if (t >= kN) return;
  int s0 = row_start[t], s1 = row_start[t + 1];
  float ern = er[t];
  float acc[32];
  #pragma unroll
  for (int q = 0; q < 8; ++q) {
    float4 v = *(const float4*)&rst[(size_t)t * 32 + q * 4];
    acc[q*4] = v.x; acc[q*4+1] = v.y; acc[q*4+2] = v.z; acc[q*4+3] = v.w;
  }
  if (s0 < s1) {
    float m = -1e30f, ssum = 0.f;
    for (int i = s0; i < s1; ++i) {
      int e = edge_ids[i];
      float lg = el[src[e]] + ern + eterm[ef[e]];
      lg = (lg < 0.f) ? 0.2f * lg : lg;
      if (lg > m) { ssum = ssum * expf(m - lg) + 1.f; m = lg; }
      else        { ssum += expf(lg - m); }
    }
    float inv = 1.f / ssum;
    for (int i = s0; i < s1; ++i) {
      int e = edge_ids[i];
      int se = src[e];
      float lg = el[se] + ern + eterm[ef[e]];
      lg = (lg < 0.f) ? 0.2f * lg : lg;
      float a = expf(lg - m) * inv;
      float f[32];
      bfrow32(&featb[(size_t)se * 32], f);
      #pragma unroll
      for (int d = 0; d < 32; ++d) acc[d] = fmaf(a, f[d], acc[d]);
    }
  }
  #pragma unroll
  for (int q = 0; q < 8; ++q)
    *(float4*)&rst[(size_t)t * 32 + q * 4] =
        make_float4(acc[q*4], acc[q*4+1], acc[q*4+2], acc[q*4+3]);
}

// ============================================================
// Final head
// ============================================================
__global__ void __launch_bounds__(256) final_kernel(
    const float* __restrict__ hfeat, const float* __restrict__ ntf,
    const int* __restrict__ node_type, const float* __restrict__ dadelta,
    const float* __restrict__ finalW, const float* __restrict__ logitsW,
    float* __restrict__ out) {
  int n = blockIdx.x * 256 + threadIdx.x;
  if (n >= kN) return;
  float delta = dadelta[0];
  const float* hf = &hfeat[(size_t)n * 32];
  const float* nt = &ntf[node_type[n] * 32];
  float a[32], b[32];
  float na = 0.f, nb = 0.f;
  #pragma unroll
  for (int d = 0; d < 32; ++d) {
    float x = hf[d];
    a[d] = x; na += x * x;
    float y = x * nt[d] + delta;
    b[d] = y; nb += y * y;
  }
  float inva = 1.f / fmaxf(sqrtf(na), 1e-12f);
  float invb = 1.f / fmaxf(sqrtf(nb), 1e-12f);
  #pragma unroll
  for (int d = 0; d < 32; ++d) { a[d] *= inva; b[d] *= invb; }
  float lg[16];
  #pragma unroll
  for (int c = 0; c < 16; ++c) lg[c] = 0.f;
  for (int o = 0; o < 32; ++o) {
    float s = 0.f;
    #pragma unroll
    for (int d = 0; d < 32; ++d)
      s += a[d] * finalW[d * 32 + o] + b[d] * finalW[(32 + d) * 32 + o];
    s = fmaxf(s, 0.f);
    #pragma unroll
    for (int c = 0; c < 16; ++c) lg[c] += s * logitsW[o * 16 + c];
  }
  float nl = 0.f;
  #pragma unroll
  for (int c = 0; c < 16; ++c) nl += lg[c] * lg[c];
  float invl = 1.f / fmaxf(sqrtf(nl), 1e-12f);
  #pragma unroll
  for (int c = 0; c < 16; ++c) out[(size_t)n * 16 + c] = lg[c] * invl;
}

// ============================================================
extern "C" void kernel_launch(void* const* d_in, const int* in_sizes, int n_in,
                              void* d_out, int out_size, void* d_ws, size_t ws_size,
                              hipStream_t stream) {
  const float* feats     = (const float*)d_in[0];
  const int*   e_feat    = (const int*)d_in[1];
  const int*   node_type = (const int*)d_in[2];
  const int*   src       = (const int*)d_in[3];
  const int*   dst       = (const int*)d_in[4];
  const float* fc_W      = (const float*)d_in[5];
  const float* fc_b      = (const float*)d_in[6];
  const float* ntype_emb = (const float*)d_in[7];
  const float* W_ntype   = (const float*)d_in[8];
  const float* ta_edge_emb[3] = {(const float*)d_in[9],  (const float*)d_in[16], (const float*)d_in[24]};
  const float* ta_W[3]        = {(const float*)d_in[10], (const float*)d_in[17], (const float*)d_in[25]};
  const float* ta_We[3]       = {(const float*)d_in[11], (const float*)d_in[18], (const float*)d_in[26]};
  const float* ta_al[3]       = {(const float*)d_in[12], (const float*)d_in[19], (const float*)d_in[27]};
  const float* ta_ar[3]       = {(const float*)d_in[13], (const float*)d_in[20], (const float*)d_in[28]};
  const float* ta_ae[3]       = {(const float*)d_in[14], (const float*)d_in[21], (const float*)d_in[29]};
  const float* ta_bias[3]     = {(const float*)d_in[15], (const float*)d_in[22], (const float*)d_in[30]};
  const float* ta1_res_W = (const float*)d_in[23];
  const float* ta2_res_W = (const float*)d_in[31];
  const float* da_ln1_b  = (const float*)d_in[33];
  const float* da_Wv     = (const float*)d_in[38];
  const float* da_bv     = (const float*)d_in[39];
  const float* da_Wo     = (const float*)d_in[40];
  const float* da_bo     = (const float*)d_in[41];
  const float* da_ln2_b  = (const float*)d_in[43];
  const float* da_W1     = (const float*)d_in[44];
  const float* da_b1     = (const float*)d_in[45];
  const float* da_W2     = (const float*)d_in[46];
  const float* da_b2     = (const float*)d_in[47];
  const float* final_W   = (const float*)d_in[48];
  const float* logits_W  = (const float*)d_in[49];
  float* out = (float*)d_out;

  // ---- workspace layout (~51.3 MB) ----
  char* base = (char*)d_ws;
  int* iws       = (int*)base;
  int* counts    = iws;
  int* cursor    = iws + kN;
  int* row_start = iws + 2 * kN;
  int* edge_ids  = iws + 2 * kN + kN + 1;
  char* p = base + (size_t)456004 * 4;
  float* ntf = (float*)p;                     p += 512;
  float* etm = (float*)p;                     p += 512;
  float* dad = (float*)p;                     p += 64;
  float* el  = (float*)p;                     p += (size_t)kN * 8 * 4;
  float* er  = (float*)p;                     p += (size_t)kN * 8 * 4;
  float* S2  = (float*)p;                     p += (size_t)kN * 32 * 4;
  u16*   Hb  = (u16*)p;                       p += (size_t)kN * 32 * 2;
  _Float16* a0h = (_Float16*)p;               p += (size_t)kE * 8 * 2;
  u16* featb = (u16*)p;                       p += (size_t)kN * 256 * 2;
  u16* Rb0   = (u16*)p;                       p += (size_t)kN * 256 * 2;
  u16* Rpr   = (u16*)p;                       p += (size_t)kN * 256 * 2;  // L1 res, then Rb1 in place
  u16* WT0   = (u16*)p;                       p += (size_t)320 * 32 * 2;
  u16* WT1   = (u16*)p;                       p += (size_t)576 * 256 * 2;
  u16* WT2   = (u16*)p;                       p += (size_t)128 * 256 * 2;

  // --- CSR build ---
  zero_ints_kernel<<<(2 * kN + 255) / 256, 256, 0, stream>>>(counts, 2 * kN);
  count_kernel<<<kE / 256, 256, 0, stream>>>(dst, counts);
  scan_kernel<<<1, 1024, 0, stream>>>(counts, row_start);
  scatter_kernel<<<kE / 256, 256, 0, stream>>>(dst, row_start, cursor, edge_ids);

  // --- precompute + weight pack ---
  precompute_kernel<<<1, 1024, 0, stream>>>(
      ntype_emb, W_ntype,
      ta_edge_emb[0], ta_We[0], ta_ae[0],
      ta_edge_emb[1], ta_We[1], ta_ae[1],
      ta_edge_emb[2], ta_We[2], ta_ae[2],
      da_ln1_b, da_Wv, da_bv, da_Wo, da_bo,
      da_ln2_b, da_W1, da_b1, da_W2, da_b2,
      ntf, etm, dad);
  pack_kernel<<<744, 256, 0, stream>>>(
      ta_W[0], ta_al[0], ta_ar[0],
      ta_W[1], ta_al[1], ta_ar[1], ta1_res_W,
      ta_W[2], ta_al[2], ta_ar[2], ta2_res_W,
      WT0, WT1, WT2);

  // --- input projection -> Hb bf16 ---
  inproj_kernel<<<(kN * 32) / 256, 256, 0, stream>>>(feats, fc_W, fc_b, ntf, node_type, Hb);

  // --- TA layer 0: GEMM (feat+el+er) then wave-agg (bias init, elu, write a0) ---
  mfma_gemm_kernel<<<dim3(5, kN / 64), 256, 0, stream>>>(
      Hb, WT0, nullptr, featb, el, er, nullptr, nullptr, 32, 256, 8, 0);
  agg8w_kernel<true, false, true, true><<<kN / 4, 256, 0, stream>>>(
      row_start, edge_ids, src, e_feat, el, er, etm, featb, ta_bias[0], a0h, nullptr, Rb0);

  // --- TA layer 1: fused GEMM (feat+el+er+res) then wave-agg (acc=res, blend a0, elu) ---
  mfma_gemm_kernel<<<dim3(9, kN / 64), 256, 0, stream>>>(
      Rb0, WT1, ta_bias[1], featb, el, er, Rpr, nullptr, 256, 256, 8, 256);
  agg8w_kernel<false, true, false, true><<<kN / 4, 256, 0, stream>>>(
      row_start, edge_ids, src, e_feat, el, er, etm + 40, featb, nullptr, a0h, Rpr, Rpr);

  // --- TA layer 2: fused GEMM (feat+el+er+res fp32) then per-thread agg (no act) ---
  mfma_gemm_kernel<<<dim3(2, kN / 64), 256, 0, stream>>>(
      Rpr, WT2, ta_bias[2], featb, el, er, nullptr, S2, 256, 32, 1, 32);
  agg1t_kernel<<<(kN + 255) / 256, 256, 0, stream>>>(
      row_start, edge_ids, src, e_feat, el, er, etm + 80, featb, S2);

  // --- DA collapse + final head ---
  final_kernel<<<(kN + 255) / 256, 256, 0, stream>>>(S2, ntf, node_type, dad, final_W, logits_W, out);
}